// Round 8
// baseline (201.913 us; speedup 1.0000x reference)
//
#include <hip/hip_runtime.h>
#include <math.h>

#define HW 16384
#define NPTS 1024
#define LOG_N 6.2383246250395075
#define RHO_C 0.09
#define SCALE_F 16384.0f
#define INV_SCALE2 3.725290298461914e-09  // 2^-28, exact
#define NTILES 36                          // 8x8 upper triangle

typedef _Float16 f16x8 __attribute__((ext_vector_type(8)));
typedef float f32x4 __attribute__((ext_vector_type(4)));

__device__ __forceinline__ void tri_map(int tt, int& ti, int& tj) {
  int a = 0, r = tt;
  while (r >= 8 - a) { r -= 8 - a; ++a; }
  ti = a; tj = a + r;
}

// ---------------------------------------------------------------------------
// Convert fp32 P=[nd;gt] (1024 x 16384) into scaled fp16 hi/lo split, stored
// fragment-native: hi2[slab = k64*2+kk][row(1024)][32]; a GEMM wave's MFMA
// fragment load (16 rows x 64B within one slab) is contiguous-per-lane ->
// coalesced global_load_dwordx4 direct to registers (no LDS).
// x_s = x*2^14 = hi + lo (exact residual; undone by 2^-28 in fp64 reduce).
// ---------------------------------------------------------------------------
__global__ __launch_bounds__(256)
void convert_split_k(const float* __restrict__ nd, const float* __restrict__ gt,
                     _Float16* __restrict__ hi2, _Float16* __restrict__ lo2) {
  const int tid = blockIdx.x * 256 + threadIdx.x;  // 0 .. 262143
  const int r = tid & 1023;
  const int k64 = tid >> 10;
  const float* __restrict__ src =
      (r < 512 ? nd + (size_t)r * HW : gt + (size_t)(r - 512) * HW) + k64 * 64;
  const size_t ob = ((size_t)k64 * 2048 + r) * 32;  // kk=0 slab; kk=1 at +1024*32
#pragma unroll
  for (int g = 0; g < 8; ++g) {
    const float4 v0 = *(const float4*)(src + g * 8);
    const float4 v1 = *(const float4*)(src + g * 8 + 4);
    const float x[8] = {v0.x, v0.y, v0.z, v0.w, v1.x, v1.y, v1.z, v1.w};
    f16x8 h, l;
#pragma unroll
    for (int j = 0; j < 8; ++j) {
      const float xs = x[j] * SCALE_F;
      const _Float16 hh = (_Float16)xs;
      h[j] = hh;
      l[j] = (_Float16)(xs - (float)hh);
    }
    const size_t o = ob + (size_t)(g >> 2) * (1024 * 32) + (g & 3) * 8;
    *(f16x8*)(hi2 + o) = h;
    *(f16x8*)(lo2 + o) = l;
  }
}

// ---------------------------------------------------------------------------
// Upper-triangle tiles only (G symmetric). 128x128 tile, 4 waves (2x2),
// 3-pass f16 split MFMA (hh + lh + hl). NO LDS; fragments loaded straight
// from global into TWO named register buffers with an explicit 2-deep
// software pipeline (round-7 showed the compiler allocates 60 VGPR and
// serializes loads without it). Next slab's 16 loads issue before current
// slab's MFMAs -> counted-vmcnt keeps them in flight under compute.
// Split-K uneven; 36 x 14 = 504 blocks: one clean dispatch wave at 2/CU.
// ---------------------------------------------------------------------------
#define LOAD_FRAGS(AH, AL, BH, BL, sidx)                                       \
  {                                                                            \
    const _Float16* __restrict__ ph_ = hi2 + (size_t)(sidx) * 32768;           \
    const _Float16* __restrict__ pl_ = lo2 + (size_t)(sidx) * 32768;           \
    _Pragma("unroll")                                                          \
    for (int m_ = 0; m_ < 4; ++m_) {                                           \
      AH[m_] = *(const f16x8*)(ph_ + abase + (size_t)m_ * 512);                \
      AL[m_] = *(const f16x8*)(pl_ + abase + (size_t)m_ * 512);                \
      BH[m_] = *(const f16x8*)(ph_ + bbase + (size_t)m_ * 512);                \
      BL[m_] = *(const f16x8*)(pl_ + bbase + (size_t)m_ * 512);                \
    }                                                                          \
  }

#define DO_MFMA(AH, AL, BH, BL)                                                \
  _Pragma("unroll")                                                            \
  for (int m_ = 0; m_ < 4; ++m_)                                               \
    _Pragma("unroll")                                                          \
    for (int n_ = 0; n_ < 4; ++n_) {                                           \
      acc[m_][n_] = __builtin_amdgcn_mfma_f32_16x16x32_f16(AH[m_], BH[n_],     \
                                                           acc[m_][n_], 0, 0, 0); \
      acc[m_][n_] = __builtin_amdgcn_mfma_f32_16x16x32_f16(AL[m_], BH[n_],     \
                                                           acc[m_][n_], 0, 0, 0); \
      acc[m_][n_] = __builtin_amdgcn_mfma_f32_16x16x32_f16(AH[m_], BL[n_],     \
                                                           acc[m_][n_], 0, 0, 0); \
    }

__global__ __launch_bounds__(256, 2)
void gemm_mfma_k(const _Float16* __restrict__ hi2, const _Float16* __restrict__ lo2,
                 float* __restrict__ part) {
  const int tt = blockIdx.x, c = blockIdx.y;
  int ti, tj;
  tri_map(tt, ti, tj);
  const int ns = gridDim.y;
  const int q = 256 / ns, rm = 256 - q * ns;
  const int kt0 = c * q + min(c, rm);
  const int nkt = q + (c < rm ? 1 : 0);
  const int t = threadIdx.x;
  const int lane = t & 63, w = t >> 6;
  const int wr = w >> 1, wc = w & 1;
  const int rlow = lane & 15, g0 = lane >> 4;

  f32x4 acc[4][4];
#pragma unroll
  for (int m = 0; m < 4; ++m)
#pragma unroll
    for (int n = 0; n < 4; ++n) acc[m][n] = (f32x4){0.f, 0.f, 0.f, 0.f};

  const size_t laneoff = (size_t)rlow * 32 + (size_t)g0 * 8;
  const size_t abase = (size_t)(ti * 128 + wr * 64) * 32 + laneoff;
  const size_t bbase = (size_t)(tj * 128 + wc * 64) * 32 + laneoff;

  const int s0 = 2 * kt0, s1 = 2 * (kt0 + nkt);  // even count of slabs
  f16x8 ah0[4], al0[4], bh0[4], bl0[4];
  f16x8 ah1[4], al1[4], bh1[4], bl1[4];

  LOAD_FRAGS(ah0, al0, bh0, bl0, s0);
  for (int s = s0; s + 2 <= s1; s += 2) {
    LOAD_FRAGS(ah1, al1, bh1, bl1, s + 1);
    DO_MFMA(ah0, al0, bh0, bl0);
    if (s + 2 < s1) LOAD_FRAGS(ah0, al0, bh0, bl0, s + 2);
    DO_MFMA(ah1, al1, bh1, bl1);
  }

  // C/D layout: col = lane&15, row = (lane>>4)*4 + q (m89-verified)
  float* __restrict__ dst = part + ((size_t)c * NTILES + tt) * 16384;
  const int c_locb = wc * 64 + rlow;
  const int r_locb = wr * 64 + g0 * 4;
#pragma unroll
  for (int m = 0; m < 4; ++m)
#pragma unroll
    for (int p = 0; p < 4; ++p) {
      const int rl = r_locb + m * 16 + p;
#pragma unroll
      for (int n = 0; n < 4; ++n)
        dst[rl * 128 + c_locb + n * 16] = acc[m][n][p];
    }
}

// ---------------------------------------------------------------------------
// Sum split-K partials (fp64), unscale, write G tile + mirrored tile (LDS
// transpose), extract diagonal. Grid: 36 tiles x 16 slabs of 8 rows = 576.
// ---------------------------------------------------------------------------
__global__ __launch_bounds__(256)
void reduce_tiles_k(const float* __restrict__ part, float* __restrict__ G,
                    float* __restrict__ diag, int nsplit) {
  __shared__ float sl[8][129];
  const int blk = blockIdx.x;  // 0..575
  const int tt = blk >> 4, s = blk & 15;
  int ti, tj;
  tri_map(tt, ti, tj);
  const int t = threadIdx.x;
  const int base_in = tt * 16384 + s * 1024;

  float vals[4];
#pragma unroll
  for (int j = 0; j < 4; ++j) {
    const int idx = j * 256 + t;  // 0..1023 within slab
    double a = 0.0;
    for (int c = 0; c < nsplit; ++c)
      a += (double)part[(size_t)c * (NTILES * 16384) + base_in + idx];
    vals[j] = (float)(a * INV_SCALE2);
  }
#pragma unroll
  for (int j = 0; j < 4; ++j) {
    const int idx = j * 256 + t;
    const int r = idx >> 7, cl = idx & 127;
    const int R = ti * 128 + s * 8 + r, C = tj * 128 + cl;
    G[(size_t)R * NPTS + C] = vals[j];
    if (R == C) diag[R] = vals[j];
    sl[r][cl] = vals[j];
  }
  if (ti == tj) return;
  __syncthreads();
#pragma unroll
  for (int j = 0; j < 4; ++j) {
    const int idx = j * 256 + t;
    const int r = idx & 7, cl = idx >> 3;
    G[(size_t)(tj * 128 + cl) * NPTS + ti * 128 + s * 8 + r] = sl[r][cl];
  }
}

// ---------------------------------------------------------------------------
// One symmetric Sinkhorn phase: 512 blocks x 4 waves; 1 wave = 1 row-task.
// pot layout: [0]=f_ba, [1]=g_ab, [2]=f_aa, [3]=g_bb (512 doubles each).
// ---------------------------------------------------------------------------
__global__ __launch_bounds__(256)
void sinkhorn_phase_k(const float* __restrict__ G, const float* __restrict__ diag,
                      const double* __restrict__ src, double* __restrict__ dst,
                      double eps, double inv_eps, double damp, int use_pot,
                      int do_avg) {
  const int w = threadIdx.x >> 6, lane = threadIdx.x & 63;
  const int id = blockIdx.x * 4 + w;  // 0..2047
  const int which = id >> 9, r = id & 511;
  int row_pt, col_base, pot_idx;
  if (which == 0)      { row_pt = r;       col_base = 512; pot_idx = 1; }
  else if (which == 1) { row_pt = 512 + r; col_base = 0;   pot_idx = 0; }
  else if (which == 2) { row_pt = r;       col_base = 0;   pot_idx = 2; }
  else                 { row_pt = 512 + r; col_base = 512; pot_idx = 3; }

  const double dr = (double)diag[row_pt];
  const double* __restrict__ pot = src + pot_idx * 512;
  const float* __restrict__ Grow = G + (size_t)row_pt * NPTS + col_base;
  const float* __restrict__ dcol = diag + col_base;

  double arg[8];
  double m = -1.0e300;
#pragma unroll
  for (int u = 0; u < 8; ++u) {
    const int j = lane + u * 64;
    const double C = 0.5 * (dr + (double)dcol[j]) - (double)Grow[j];
    const double p = use_pot ? pot[j] : 0.0;
    const double a = (p - C) * inv_eps - LOG_N;
    arg[u] = a;
    m = fmax(m, a);
  }
#pragma unroll
  for (int off = 32; off > 0; off >>= 1) m = fmax(m, __shfl_xor(m, off));
  double s = 0.0;
#pragma unroll
  for (int u = 0; u < 8; ++u) s += exp(arg[u] - m);
#pragma unroll
  for (int off = 32; off > 0; off >>= 1) s += __shfl_xor(s, off);
  if (lane == 0) {
    const double lse = m + log(s);
    const double val = -eps * lse * damp;
    dst[which * 512 + r] = do_avg ? 0.5 * (src[which * 512 + r] + val) : val;
  }
}

// ---------------------------------------------------------------------------
// Debiased unbalanced Sinkhorn loss.
// ---------------------------------------------------------------------------
__global__ __launch_bounds__(256)
void loss_k(const double* __restrict__ pot, float* __restrict__ out, int out_size,
            double w) {
  const int t = threadIdx.x;
  double s = 0.0;
  for (int i = t; i < 512; i += 256) {
    s += (exp(-pot[1024 + i] / RHO_C) - exp(-pot[i] / RHO_C)) +
         (exp(-pot[1536 + i] / RHO_C) - exp(-pot[512 + i] / RHO_C));
  }
#pragma unroll
  for (int off = 32; off > 0; off >>= 1) s += __shfl_xor(s, off);
  __shared__ double wsum[4];
  if ((t & 63) == 0) wsum[t >> 6] = s;
  __syncthreads();
  if (t == 0) {
    out[0] = (float)(w * (wsum[0] + wsum[1] + wsum[2] + wsum[3]) * (1.0 / 512.0));
    for (int i = 1; i < out_size; ++i) out[i] = 0.f;
  }
}

extern "C" void kernel_launch(void* const* d_in, const int* in_sizes, int n_in,
                              void* d_out, int out_size, void* d_ws, size_t ws_size,
                              hipStream_t stream) {
  const float* nd = (const float*)d_in[1];
  const float* gt = (const float*)d_in[2];
  float* out = (float*)d_out;
  char* ws = (char*)d_ws;

  const size_t GM = (size_t)NPTS * NPTS;     // 1M elems
  const size_t P16 = (size_t)NPTS * HW * 2;  // 32 MB per half
  int nsplit = 14;                            // 36*14 = 504 blocks: no tail
  while (nsplit > 1 &&
         2 * P16 + (size_t)nsplit * NTILES * 16384 * 4 + GM * 4 + 65536 > ws_size)
    nsplit >>= 1;

  _Float16* hi2 = (_Float16*)ws;
  _Float16* lo2 = (_Float16*)(ws + P16);
  float* part = (float*)(ws + 2 * P16);
  const size_t partsz = (size_t)nsplit * NTILES * 16384 * 4;
  float* G = (float*)(ws + 2 * P16 + partsz);
  float* diag = (float*)(ws + 2 * P16 + partsz + GM * 4);
  double* pots = (double*)(ws + 2 * P16 + partsz + GM * 4 + 8192);

  convert_split_k<<<1024, 256, 0, stream>>>(nd, gt, hi2, lo2);
  gemm_mfma_k<<<dim3(NTILES, nsplit), 256, 0, stream>>>(hi2, lo2, part);
  reduce_tiles_k<<<576, 256, 0, stream>>>(part, G, diag, nsplit);

  const double eps_list[9] = {1.0, 1.0, 0.25, 0.0625, 0.015625,
                              0.00390625, 0.0009765625, 0.000244140625, 1e-4};
  double* p0 = pots;
  double* p1 = pots + 2048;
  {  // init at eps0 = 1.0, no inner potentials, no averaging
    const double eps = 1.0, d = 1.0 / (1.0 + eps / RHO_C);
    sinkhorn_phase_k<<<512, 256, 0, stream>>>(G, diag, p1, p0, eps, 1.0 / eps, d, 0, 0);
  }
  double* src = p0;
  double* dst = p1;
  for (int k = 0; k < 9; ++k) {  // symmetric averaged updates
    const double eps = eps_list[k], d = 1.0 / (1.0 + eps / RHO_C);
    sinkhorn_phase_k<<<512, 256, 0, stream>>>(G, diag, src, dst, eps, 1.0 / eps, d, 1, 1);
    double* tmp = src; src = dst; dst = tmp;
  }
  {  // final extrapolation at blur^2, no averaging
    const double eps = 1e-4, d = 1.0 / (1.0 + eps / RHO_C);
    sinkhorn_phase_k<<<512, 256, 0, stream>>>(G, diag, src, dst, eps, 1.0 / eps, d, 1, 0);
    double* tmp = src; src = dst; dst = tmp;
  }
  loss_k<<<1, 256, 0, stream>>>(src, out, out_size, RHO_C + 1e-4 * 0.5);
}